// Round 2
// baseline (38.232 us; speedup 1.0000x reference)
//
#include <hip/hip_runtime.h>
#include <math.h>

// VectorQuantizer: B=4, T=2048, DIM=64, NUM_CODES=512
// out = [ k as float (8192) | z_q (8192*64) ]
//
// Structure: lane = query (64 queries/wave, query vector in 64 VGPRs),
// codes split into NSPLIT chunks staged in LDS (broadcast ds_read_b128).
// Distance math is bit-identical to the validated round-0 kernel
// (8-accumulator tree + IEEE sqrtf + strict-< ascending-index argmin).

#define NQ      8192
#define VDIM    64
#define NCODES  512

template <int NSPLIT>
__global__ __launch_bounds__(256, 4) void vq_partial_kernel(
    const float* __restrict__ inp,     // [NQ][VDIM]
    const float* __restrict__ table,   // [NCODES][VDIM]
    float* __restrict__ wnorm,         // [NSPLIT][NQ]
    int* __restrict__ widx)            // [NSPLIT][NQ]
{
    constexpr int CPC = NCODES / NSPLIT;          // codes per chunk
    __shared__ float lcode[CPC * VDIM];           // 4 KB (NSPLIT=32) / 8 KB (16)

    const int lane  = threadIdx.x & 63;
    const int wave  = threadIdx.x >> 6;           // 0..3 -> qgroup within quad
    const int chunk = blockIdx.x % NSPLIT;        // code chunk (fast dim)
    const int qquad = blockIdx.x / NSPLIT;        // 0..31 (4 qgroups each)
    const int q     = qquad * 256 + wave * 64 + lane;

    // --- Stage this chunk's code rows into LDS (coalesced float4) ---
    {
        const float4* src = reinterpret_cast<const float4*>(table + (size_t)chunk * CPC * VDIM);
        float4* dst = reinterpret_cast<float4*>(lcode);
        constexpr int NV4 = CPC * VDIM / 4;       // 256 or 512
#pragma unroll
        for (int i = threadIdx.x; i < NV4; i += 256) dst[i] = src[i];
    }
    __syncthreads();

    // --- Query vector into registers ---
    float qv[VDIM];
    {
        const float4* qp = reinterpret_cast<const float4*>(inp + (size_t)q * VDIM);
#pragma unroll
        for (int i = 0; i < 16; ++i) {
            float4 v = qp[i];
            qv[4*i+0] = v.x; qv[4*i+1] = v.y; qv[4*i+2] = v.z; qv[4*i+3] = v.w;
        }
    }

    float best = INFINITY;
    int   bidx = 0;

#pragma unroll 2
    for (int c = 0; c < CPC; ++c) {
        const float4* crow = reinterpret_cast<const float4*>(&lcode[c * VDIM]);
        float acc[8];
#pragma unroll
        for (int j = 0; j < 8; ++j) acc[j] = 0.0f;
#pragma unroll
        for (int i = 0; i < 16; ++i) {
            float4 cv = crow[i];                  // wave-uniform addr -> LDS broadcast
            float d0 = qv[4*i+0] - cv.x;
            float d1 = qv[4*i+1] - cv.y;
            float d2 = qv[4*i+2] - cv.z;
            float d3 = qv[4*i+3] - cv.w;
            acc[(4*i+0) & 7] = __builtin_fmaf(d0, d0, acc[(4*i+0) & 7]);
            acc[(4*i+1) & 7] = __builtin_fmaf(d1, d1, acc[(4*i+1) & 7]);
            acc[(4*i+2) & 7] = __builtin_fmaf(d2, d2, acc[(4*i+2) & 7]);
            acc[(4*i+3) & 7] = __builtin_fmaf(d3, d3, acc[(4*i+3) & 7]);
        }
        float s = ((acc[0] + acc[1]) + (acc[2] + acc[3]))
                + ((acc[4] + acc[5]) + (acc[6] + acc[7]));
        float n = sqrtf(s);                       // same norm-space compare as ref
        if (n < best) {                           // strict <, ascending c
            best = n;
            bidx = chunk * CPC + c;
        }
    }

    wnorm[(size_t)chunk * NQ + q] = best;
    widx [(size_t)chunk * NQ + q] = bidx;
}

// Reduce partials per query (ascending chunk -> lowest-index tie-break),
// write k (as float) and gather z_q coalesced.
__global__ __launch_bounds__(256) void vq_finalize_kernel(
    const float* __restrict__ table,
    const float* __restrict__ wnorm,
    const int* __restrict__ widx,
    float* __restrict__ out,
    int nsplit)
{
    const int gid = blockIdx.x * 256 + threadIdx.x;   // 0 .. NQ*64
    const int q = gid >> 6;
    const int d = gid & 63;

    float best = INFINITY;
    int   bidx = 0;
    for (int p = 0; p < nsplit; ++p) {
        float n = wnorm[(size_t)p * NQ + q];
        int   i = widx [(size_t)p * NQ + q];
        if (n < best) { best = n; bidx = i; }
    }

    out[NQ + (size_t)q * VDIM + d] = table[(size_t)bidx * VDIM + d];
    if (d == 0) out[q] = (float)bidx;
}

extern "C" void kernel_launch(void* const* d_in, const int* in_sizes, int n_in,
                              void* d_out, int out_size, void* d_ws, size_t ws_size,
                              hipStream_t stream) {
    const float* inp   = (const float*)d_in[0];   // [4,2048,64] fp32
    const float* table = (const float*)d_in[1];   // [512,64]    fp32
    float* out = (float*)d_out;

    // Pick split by available workspace (deterministic: ws_size is fixed).
    if (ws_size >= (size_t)32 * NQ * 8) {
        const int NS = 32;
        float* wnorm = (float*)d_ws;
        int*   widx  = (int*)(wnorm + (size_t)NS * NQ);
        vq_partial_kernel<32><<<dim3(32 * NS), dim3(256), 0, stream>>>(inp, table, wnorm, widx);
        vq_finalize_kernel<<<dim3((NQ * VDIM) / 256), dim3(256), 0, stream>>>(table, wnorm, widx, out, NS);
    } else {
        const int NS = 16;
        float* wnorm = (float*)d_ws;
        int*   widx  = (int*)(wnorm + (size_t)NS * NQ);
        vq_partial_kernel<16><<<dim3(32 * NS), dim3(256), 0, stream>>>(inp, table, wnorm, widx);
        vq_finalize_kernel<<<dim3((NQ * VDIM) / 256), dim3(256), 0, stream>>>(table, wnorm, widx, out, NS);
    }
}